// Round 11
// baseline (1182.494 us; speedup 1.0000x reference)
//
#include <hip/hip_runtime.h>

#define SEQ   512
#define BATCH 64
#define HID   1024
#define NX    8
#define SG    16     // s-groups per batch (attention); 32 rows each
#define SB    8      // rows per register batch
#define NBAT  4      // 4*8 = 32 rows per attn block

// ---------------------------------------------------------------------------
// WVT[h][n] = WV[n][h]  (one-time 32x32 tiled transpose)
// ---------------------------------------------------------------------------
__global__ __launch_bounds__(256) void transpose_k(
    const float* __restrict__ in, float* __restrict__ outT)
{
    __shared__ float tile[32][33];
    const int bx = blockIdx.x * 32, by = blockIdx.y * 32;
    const int tx = threadIdx.x & 31, ty = threadIdx.x >> 5;
    #pragma unroll
    for (int r = ty; r < 32; r += 8)
        tile[r][tx] = in[(size_t)(by + r) * HID + bx + tx];
    __syncthreads();
    #pragma unroll
    for (int r = ty; r < 32; r += 8)
        outT[(size_t)(bx + r) * HID + by + tx] = tile[tx][r];
}

// ---------------------------------------------------------------------------
// gemv_y: y[b, n] = sum_j x[b,j] * WK[j,n]   COMPLETE output. (round-7 exact)
// grid dim3(nc=32, b=64). x = opfull + bV (q at t==1) staged in LDS;
// nc==0 writes out row t-1.
// ---------------------------------------------------------------------------
__global__ __launch_bounds__(256) void gemv_y_kernel(
    const float* __restrict__ WK, const float* __restrict__ q,
    const float* __restrict__ opfull, const float* __restrict__ bV,
    float* __restrict__ out, int t, float* __restrict__ y)
{
    __shared__ float xs[HID];
    __shared__ float red[8][32];
    const int nc = blockIdx.x, b = blockIdx.y;
    const int tid = threadIdx.x;
    const int h4 = tid * 4;

    {
        float4 v;
        if (t == 1) {
            v = *(const float4*)(q + (size_t)b * HID + h4);
        } else {
            float4 o  = *(const float4*)(opfull + (size_t)b * HID + h4);
            float4 bb = *(const float4*)(bV + h4);
            v.x = o.x + bb.x; v.y = o.y + bb.y;
            v.z = o.z + bb.z; v.w = o.w + bb.w;
        }
        *(float4*)(xs + h4) = v;
        if (nc == 0)
            *(float4*)(out + ((size_t)(b * NX + t - 1)) * HID + h4) = v;
    }
    __syncthreads();

    const int nl = tid & 31, jg = tid >> 5;
    const int n = nc * 32 + nl;
    const float* __restrict__ wp = WK + (size_t)(jg * 128) * HID + n;
    const float* __restrict__ xr = xs + jg * 128;
    float acc = 0.f;
    #pragma unroll 8
    for (int jj = 0; jj < 128; jj++)
        acc += xr[jj] * wp[(size_t)jj * HID];
    red[jg][nl] = acc;
    __syncthreads();
    if (tid < 32) {
        float s = 0.f;
        #pragma unroll
        for (int g = 0; g < 8; g++) s += red[g][tid];
        y[(size_t)b * HID + nc * 32 + tid] = s;
    }
}

// ---------------------------------------------------------------------------
// fused_attn + last-block finalize: grid dim3(sg=16, b=64).
// Each block: 32 rows online-flash -> zp[b,sg,:], ml[b,sg].
// The LAST block for b (device-scope counter) re-reads zp[b] once and writes
// the globally-normalized z[b,:].
// ---------------------------------------------------------------------------
__global__ __launch_bounds__(256) void fused_attn_kernel(
    const float* __restrict__ hidden, const float* __restrict__ y,
    float* __restrict__ zp, float* __restrict__ ml,
    float* __restrict__ z, unsigned* __restrict__ done)
{
    const int sg = blockIdx.x, b = blockIdx.y;
    const int tid = threadIdx.x;
    const int lane = tid & 63, w = tid >> 6;
    const int h4 = tid * 4;

    __shared__ float part[4][SB];
    __shared__ float mls[2 * SG];
    __shared__ int lastflag;

    const float4 yv = *(const float4*)(y + (size_t)b * HID + h4);
    float m = -1e30f, l = 0.f;
    float4 acc = {0.f, 0.f, 0.f, 0.f};

    #pragma unroll
    for (int bb = 0; bb < NBAT; bb++) {
        float4 hv[SB];
        float p[SB];
        #pragma unroll
        for (int r = 0; r < SB; r++) {
            const int s = sg * 32 + bb * SB + r;
            hv[r] = *(const float4*)(hidden + ((size_t)s * BATCH + b) * HID + h4);
            p[r] = hv[r].x * yv.x + hv[r].y * yv.y
                 + hv[r].z * yv.z + hv[r].w * yv.w;
        }
        #pragma unroll
        for (int r = 0; r < SB; r++) {
            float s = p[r];
            #pragma unroll
            for (int off = 32; off; off >>= 1) s += __shfl_xor(s, off);
            if (lane == 0) part[w][r] = s;
        }
        __syncthreads();
        float sc[SB], mb = -1e30f;
        #pragma unroll
        for (int r = 0; r < SB; r++) {
            sc[r] = part[0][r] + part[1][r] + part[2][r] + part[3][r];
            mb = fmaxf(mb, sc[r]);
        }
        __syncthreads();
        const float newm  = fmaxf(m, mb);
        const float scale = __expf(m - newm);
        l *= scale;
        acc.x *= scale; acc.y *= scale; acc.z *= scale; acc.w *= scale;
        #pragma unroll
        for (int r = 0; r < SB; r++) {
            const float we = __expf(sc[r] - newm);
            l += we;
            acc.x += we * hv[r].x; acc.y += we * hv[r].y;
            acc.z += we * hv[r].z; acc.w += we * hv[r].w;
        }
        m = newm;
    }
    *(float4*)(zp + ((size_t)(b * SG + sg)) * HID + h4) = acc;
    if (tid == 0) {
        ml[(b * SG + sg) * 2 + 0] = m;
        ml[(b * SG + sg) * 2 + 1] = l;
    }

    // ---- last-block global softmax finalize ----
    __threadfence();                       // release this block's zp/ml
    __syncthreads();
    if (tid == 0) {
        const unsigned prev = __hip_atomic_fetch_add(
            &done[b], 1u, __ATOMIC_ACQ_REL, __HIP_MEMORY_SCOPE_AGENT);
        lastflag = (prev == (unsigned)(SG - 1));
    }
    __syncthreads();
    if (!lastflag) return;
    (void)__hip_atomic_load(&done[b], __ATOMIC_ACQUIRE,
                            __HIP_MEMORY_SCOPE_AGENT);   // per-thread acquire

    if (tid < 2 * SG) mls[tid] = ml[b * 2 * SG + tid];
    __syncthreads();

    float M = -1e30f;
    #pragma unroll
    for (int g = 0; g < SG; g++) M = fmaxf(M, mls[2 * g]);
    float es[SG], L = 0.f;
    #pragma unroll
    for (int g = 0; g < SG; g++) {
        es[g] = __expf(mls[2 * g] - M);
        L += mls[2 * g + 1] * es[g];
    }
    const float invL = 1.0f / L;

    float4 zv = {0.f, 0.f, 0.f, 0.f};
    #pragma unroll
    for (int g = 0; g < SG; g++) {
        const float4 v = *(const float4*)(zp + ((size_t)(b * SG + g)) * HID + h4);
        zv.x += es[g] * v.x; zv.y += es[g] * v.y;
        zv.z += es[g] * v.z; zv.w += es[g] * v.w;
    }
    zv.x *= invL; zv.y *= invL; zv.z *= invL; zv.w *= invL;
    *(float4*)(z + (size_t)b * HID + h4) = zv;
}

// ---------------------------------------------------------------------------
// gemv_out: opfull[b, n] = sum_h z[b,h] * WVT[h,n]   COMPLETE. (round-7 exact)
// grid dim3(nc=32, b=64); z (4 KB) staged in LDS.
// ---------------------------------------------------------------------------
__global__ __launch_bounds__(256) void gemv_out_kernel(
    const float* __restrict__ WVT, const float* __restrict__ z,
    float* __restrict__ opfull)
{
    __shared__ float zs[HID];
    __shared__ float red[8][32];
    const int nc = blockIdx.x, b = blockIdx.y;
    const int tid = threadIdx.x;

    *(float4*)(zs + tid * 4) = *(const float4*)(z + (size_t)b * HID + tid * 4);
    __syncthreads();

    const int nl = tid & 31, hg = tid >> 5;
    const int n  = nc * 32 + nl;
    const float* __restrict__ wp = WVT + (size_t)(hg * 128) * HID + n;
    const float* __restrict__ zr = zs + hg * 128;
    float acc = 0.f;
    #pragma unroll 8
    for (int hh = 0; hh < 128; hh++)
        acc += zr[hh] * wp[(size_t)hh * HID];
    red[hg][nl] = acc;
    __syncthreads();
    if (tid < 32) {
        float s = 0.f;
        #pragma unroll
        for (int g = 0; g < 8; g++) s += red[g][tid];
        opfull[(size_t)b * HID + nc * 32 + tid] = s;
    }
}

// final output row t=NX-1: out = opfull + bias
__global__ __launch_bounds__(256) void final_out_kernel(
    const float* __restrict__ opfull, const float* __restrict__ bias,
    float* __restrict__ out)
{
    const int idx = blockIdx.x * 256 + threadIdx.x;
    const int b = idx >> 10, n = idx & (HID - 1);
    out[((size_t)(b * NX + NX - 1)) * HID + n] = opfull[idx] + bias[n];
}

// ---------------------------------------------------------------------------
extern "C" void kernel_launch(void* const* d_in, const int* in_sizes, int n_in,
                              void* d_out, int out_size, void* d_ws, size_t ws_size,
                              hipStream_t stream)
{
    const float* hidden = (const float*)d_in[1];
    const float* q      = (const float*)d_in[2];
    const float* WK     = (const float*)d_in[3];
    const float* WV     = (const float*)d_in[5];
    const float* bV     = (const float*)d_in[6];
    float* out = (float*)d_out;

    char* ws = (char*)d_ws;
    float*    WVT    = (float*)(ws);                              // 4 MiB
    float*    zp     = (float*)(ws + (4 << 20));                  // 4 MiB
    float*    y      = (float*)(ws + (8 << 20));                  // 256 KiB
    float*    z      = (float*)(ws + (8 << 20) + (256 << 10));    // 256 KiB
    float*    opfull = (float*)(ws + (8 << 20) + (512 << 10));    // 256 KiB
    float*    ml     = (float*)(ws + (8 << 20) + (768 << 10));    // 8 KiB
    unsigned* done   = (unsigned*)(ws + (9 << 20));               // 7*64 u32

    hipMemsetAsync(done, 0, (NX - 1) * BATCH * sizeof(unsigned), stream);
    transpose_k<<<dim3(32, 32), 256, 0, stream>>>(WV, WVT);

    for (int t = 1; t < NX; t++) {
        gemv_y_kernel<<<dim3(32, BATCH), 256, 0, stream>>>(
            WK, q, opfull, bV, out, t, y);
        fused_attn_kernel<<<dim3(SG, BATCH), 256, 0, stream>>>(
            hidden, y, zp, ml, z, done + (size_t)(t - 1) * BATCH);
        gemv_out_kernel<<<dim3(32, BATCH), 256, 0, stream>>>(
            WVT, z, opfull);
    }
    final_out_kernel<<<(BATCH * HID) / 256, 256, 0, stream>>>(opfull, bV, out);
}

// Round 12
// 583.583 us; speedup vs baseline: 2.0263x; 2.0263x over previous
//
#include <hip/hip_runtime.h>

#define SEQ   512
#define BATCH 64
#define HID   1024
#define NX    8
#define SG    8      // s-groups per batch (attention); 64 rows each
#define SB    8      // rows per register batch
#define NBAT  8      // 8*8 = 64 rows per attn block

// ---------------------------------------------------------------------------
// WVT[h][n] = WV[n][h]  (one-time 32x32 tiled transpose)
// ---------------------------------------------------------------------------
__global__ __launch_bounds__(256) void transpose_k(
    const float* __restrict__ in, float* __restrict__ outT)
{
    __shared__ float tile[32][33];
    const int bx = blockIdx.x * 32, by = blockIdx.y * 32;
    const int tx = threadIdx.x & 31, ty = threadIdx.x >> 5;
    #pragma unroll
    for (int r = ty; r < 32; r += 8)
        tile[r][tx] = in[(size_t)(by + r) * HID + bx + tx];
    __syncthreads();
    #pragma unroll
    for (int r = ty; r < 32; r += 8)
        outT[(size_t)(bx + r) * HID + by + tx] = tile[tx][r];
}

// ---------------------------------------------------------------------------
// wc_gemm: WC[h,n] = sum_j WV[j,h] * WK[j,n]   (= WVT x WK), one-time.
// Also bc[n] = sum_j bV[j] * WK[j,n] (computed by mt==0 blocks).
// grid (nt=16, mt=16); block 256 = 4 waves; 64x64 tile; K-chunk 32.
// A staged transposed in LDS; A-reads are wave-uniform (broadcast).
// ---------------------------------------------------------------------------
__global__ __launch_bounds__(256) void wc_gemm(
    const float* __restrict__ WV, const float* __restrict__ WK,
    const float* __restrict__ bV, float* __restrict__ WC,
    float* __restrict__ bc)
{
    __shared__ float As[64][36];
    const int nt = blockIdx.x, mt = blockIdx.y;
    const int tid = threadIdx.x;
    const int rg = tid >> 6, nl = tid & 63;

    float acc[16] = {};
    float accbc = 0.f;

    for (int k0 = 0; k0 < HID; k0 += 32) {
        {   // stage A chunk: As[h][j] = WV[k0+j][mt*64+h]
            const int j = tid >> 3, h8 = (tid & 7) * 8;
            const float* src = WV + (size_t)(k0 + j) * HID + mt * 64 + h8;
            float4 a0 = *(const float4*)(src);
            float4 a1 = *(const float4*)(src + 4);
            As[h8 + 0][j] = a0.x; As[h8 + 1][j] = a0.y;
            As[h8 + 2][j] = a0.z; As[h8 + 3][j] = a0.w;
            As[h8 + 4][j] = a1.x; As[h8 + 5][j] = a1.y;
            As[h8 + 6][j] = a1.z; As[h8 + 7][j] = a1.w;
        }
        __syncthreads();

        #pragma unroll
        for (int kk4 = 0; kk4 < 8; kk4++) {
            const int k = k0 + kk4 * 4;
            const float b0 = WK[(size_t)(k + 0) * HID + nt * 64 + nl];
            const float b1 = WK[(size_t)(k + 1) * HID + nt * 64 + nl];
            const float b2 = WK[(size_t)(k + 2) * HID + nt * 64 + nl];
            const float b3 = WK[(size_t)(k + 3) * HID + nt * 64 + nl];
            #pragma unroll
            for (int i = 0; i < 16; i++) {
                const float4 a = *(const float4*)&As[rg * 16 + i][kk4 * 4];
                acc[i] += a.x * b0 + a.y * b1 + a.z * b2 + a.w * b3;
            }
            if (mt == 0)
                accbc += bV[k + 0] * b0 + bV[k + 1] * b1
                       + bV[k + 2] * b2 + bV[k + 3] * b3;
        }
        __syncthreads();
    }

    #pragma unroll
    for (int i = 0; i < 16; i++)
        WC[(size_t)(mt * 64 + rg * 16 + i) * HID + nt * 64 + nl] = acc[i];
    if (mt == 0 && rg == 0) bc[nt * 64 + nl] = accbc;
}

// ---------------------------------------------------------------------------
// y_kernel: y[b,n] = sum_h x[b,h] * W[h,n] (+ bc[n])
// mode 0 (t==1): x = q, W = WK, no bc.
// mode 1 (t>=2): x = rescale(zp, ml)  (global-softmax z), W = WC, + bc;
//                nc==0 also writes z to zs_slot (for the final out GEMM).
// grid (nc=32, b=64); block 256 = 8 jg x 32 nl.
// ---------------------------------------------------------------------------
__global__ __launch_bounds__(256) void y_kernel(
    const float* __restrict__ W, const float* __restrict__ q,
    const float* __restrict__ zp, const float* __restrict__ ml,
    const float* __restrict__ bc, float* __restrict__ zs_slot,
    float* __restrict__ y, int mode)
{
    __shared__ float xs[HID];
    __shared__ float red[8][32];
    const int nc = blockIdx.x, b = blockIdx.y;
    const int tid = threadIdx.x;

    if (mode == 0) {
        *(float4*)(xs + tid * 4) = *(const float4*)(q + (size_t)b * HID + tid * 4);
    } else {
        float M = -1e30f;
        #pragma unroll
        for (int g = 0; g < SG; g++) M = fmaxf(M, ml[b * 2 * SG + 2 * g]);
        float es[SG], L = 0.f;
        #pragma unroll
        for (int g = 0; g < SG; g++) {
            es[g] = __expf(ml[b * 2 * SG + 2 * g] - M);
            L += ml[b * 2 * SG + 2 * g + 1] * es[g];
        }
        const float invL = 1.0f / L;
        for (int i = tid; i < HID; i += 256) {
            float s = 0.f;
            #pragma unroll
            for (int g = 0; g < SG; g++)
                s += zp[((size_t)(b * SG + g)) * HID + i] * es[g];
            s *= invL;
            xs[i] = s;
            if (nc == 0 && zs_slot) zs_slot[(size_t)b * HID + i] = s;
        }
    }
    __syncthreads();

    const int nl = tid & 31, jg = tid >> 5;
    const int n = nc * 32 + nl;
    const float* __restrict__ wp = W + (size_t)(jg * 128) * HID + n;
    const float* __restrict__ xr = xs + jg * 128;
    float acc = 0.f;
    #pragma unroll 8
    for (int jj = 0; jj < 128; jj++)
        acc += xr[jj] * wp[(size_t)jj * HID];
    red[jg][nl] = acc;
    __syncthreads();
    if (tid < 32) {
        float s = 0.f;
        #pragma unroll
        for (int g = 0; g < 8; g++) s += red[g][tid];
        if (mode != 0) s += bc[nc * 32 + tid];
        y[(size_t)b * HID + nc * 32 + tid] = s;
    }
}

// ---------------------------------------------------------------------------
// fused_attn: grid (sg=8, b=64). 64 rows/block, online (m,l) flash; hidden
// rows in registers. Writes zp[b,sg,:] (unnormalized) and ml[b,sg]=(m,l).
// No fences, no atomics.
// ---------------------------------------------------------------------------
__global__ __launch_bounds__(256) void fused_attn_kernel(
    const float* __restrict__ hidden, const float* __restrict__ y,
    float* __restrict__ zp, float* __restrict__ ml)
{
    const int sg = blockIdx.x, b = blockIdx.y;
    const int tid = threadIdx.x;
    const int lane = tid & 63, w = tid >> 6;
    const int h4 = tid * 4;

    __shared__ float part[4][SB];

    const float4 yv = *(const float4*)(y + (size_t)b * HID + h4);
    float m = -1e30f, l = 0.f;
    float4 acc = {0.f, 0.f, 0.f, 0.f};

    for (int bb = 0; bb < NBAT; bb++) {
        float4 hv[SB];
        float p[SB];
        #pragma unroll
        for (int r = 0; r < SB; r++) {
            const int s = sg * 64 + bb * SB + r;
            hv[r] = *(const float4*)(hidden + ((size_t)s * BATCH + b) * HID + h4);
            p[r] = hv[r].x * yv.x + hv[r].y * yv.y
                 + hv[r].z * yv.z + hv[r].w * yv.w;
        }
        #pragma unroll
        for (int r = 0; r < SB; r++) {
            float s = p[r];
            #pragma unroll
            for (int off = 32; off; off >>= 1) s += __shfl_xor(s, off);
            if (lane == 0) part[w][r] = s;
        }
        __syncthreads();
        float sc[SB], mb = -1e30f;
        #pragma unroll
        for (int r = 0; r < SB; r++) {
            sc[r] = part[0][r] + part[1][r] + part[2][r] + part[3][r];
            mb = fmaxf(mb, sc[r]);
        }
        __syncthreads();
        const float newm  = fmaxf(m, mb);
        const float scale = __expf(m - newm);
        l *= scale;
        acc.x *= scale; acc.y *= scale; acc.z *= scale; acc.w *= scale;
        #pragma unroll
        for (int r = 0; r < SB; r++) {
            const float we = __expf(sc[r] - newm);
            l += we;
            acc.x += we * hv[r].x; acc.y += we * hv[r].y;
            acc.z += we * hv[r].z; acc.w += we * hv[r].w;
        }
        m = newm;
    }
    *(float4*)(zp + ((size_t)(b * SG + sg)) * HID + h4) = acc;
    if (tid == 0) {
        ml[(b * SG + sg) * 2 + 0] = m;
        ml[(b * SG + sg) * 2 + 1] = l;
    }
}

// ---------------------------------------------------------------------------
// final_gemm: out rows 1..7: out[b,s,n] = sum_h z_s[b,h]*WVT[h,n] + bV[n];
// z_s from zs slots (s=1..6) or from zp/ml (s=7). Row 0 = q.
// grid (nc=32, b=64); block 256 = 8 hg x 32 nl.
// ---------------------------------------------------------------------------
__global__ __launch_bounds__(256) void final_gemm(
    const float* __restrict__ WVT, const float* __restrict__ zs,
    const float* __restrict__ zp, const float* __restrict__ ml,
    const float* __restrict__ q, const float* __restrict__ bV,
    float* __restrict__ out)
{
    __shared__ float zst[7][HID];     // 28 KiB
    __shared__ float red[8][7][32];   // 7 KiB
    const int nc = blockIdx.x, b = blockIdx.y;
    const int tid = threadIdx.x;

    // es/invL for step-7 z (same arithmetic as y_kernel mode 1)
    float M = -1e30f;
    #pragma unroll
    for (int g = 0; g < SG; g++) M = fmaxf(M, ml[b * 2 * SG + 2 * g]);
    float es[SG], L = 0.f;
    #pragma unroll
    for (int g = 0; g < SG; g++) {
        es[g] = __expf(ml[b * 2 * SG + 2 * g] - M);
        L += ml[b * 2 * SG + 2 * g + 1] * es[g];
    }
    const float invL = 1.0f / L;

    for (int i = tid; i < 7 * HID; i += 256) {
        const int si = i >> 10;          // 0..6  (step s = si+1)
        const int h  = i & (HID - 1);
        float v;
        if (si < 6) {
            v = zs[((size_t)si * BATCH + b) * HID + h];
        } else {
            v = 0.f;
            #pragma unroll
            for (int g = 0; g < SG; g++)
                v += zp[((size_t)(b * SG + g)) * HID + h] * es[g];
            v *= invL;
        }
        zst[si][h] = v;
    }
    __syncthreads();

    const int nl = tid & 31, hg = tid >> 5;
    const int n = nc * 32 + nl;
    const float* __restrict__ wp = WVT + (size_t)(hg * 128) * HID + n;
    float acc[7] = {};
    #pragma unroll 4
    for (int hh = 0; hh < 128; hh++) {
        const float wv = wp[(size_t)hh * HID];
        const int h = hg * 128 + hh;
        #pragma unroll
        for (int si = 0; si < 7; si++)
            acc[si] += zst[si][h] * wv;
    }
    #pragma unroll
    for (int si = 0; si < 7; si++) red[hg][si][nl] = acc[si];
    __syncthreads();

    if (tid < 224) {
        const int si = tid >> 5, nl2 = tid & 31;
        const int n2 = nc * 32 + nl2;
        float s = bV[n2];
        #pragma unroll
        for (int g = 0; g < 8; g++) s += red[g][si][nl2];
        out[((size_t)(b * NX + si + 1)) * HID + n2] = s;
    } else {
        const int nl2 = tid - 224;
        const int n2 = nc * 32 + nl2;
        out[((size_t)(b * NX)) * HID + n2] = q[(size_t)b * HID + n2];
    }
}

// ---------------------------------------------------------------------------
extern "C" void kernel_launch(void* const* d_in, const int* in_sizes, int n_in,
                              void* d_out, int out_size, void* d_ws, size_t ws_size,
                              hipStream_t stream)
{
    const float* hidden = (const float*)d_in[1];
    const float* q      = (const float*)d_in[2];
    const float* WK     = (const float*)d_in[3];
    const float* WV     = (const float*)d_in[5];
    const float* bV     = (const float*)d_in[6];
    float* out = (float*)d_out;

    char* ws = (char*)d_ws;
    float* WVT = (float*)(ws);                               // 4 MiB
    float* WC  = (float*)(ws + (4  << 20));                  // 4 MiB
    float* zp  = (float*)(ws + (8  << 20));                  // 2 MiB
    float* zs  = (float*)(ws + (10 << 20));                  // 6 slots, 1.5 MiB
    float* y   = (float*)(ws + (12 << 20));                  // 256 KiB
    float* ml  = (float*)(ws + (12 << 20) + (256 << 10));    // 4 KiB
    float* bc  = (float*)(ws + (12 << 20) + (512 << 10));    // 4 KiB

    transpose_k<<<dim3(32, 32), 256, 0, stream>>>(WV, WVT);
    wc_gemm<<<dim3(16, 16), 256, 0, stream>>>(WV, WK, bV, WC, bc);

    for (int t = 1; t < NX; t++) {
        if (t == 1) {
            y_kernel<<<dim3(32, BATCH), 256, 0, stream>>>(
                WK, q, nullptr, nullptr, nullptr, nullptr, y, 0);
        } else {
            float* slot = (t <= 7) ? zs + (size_t)(t - 2) * BATCH * HID : nullptr;
            y_kernel<<<dim3(32, BATCH), 256, 0, stream>>>(
                WC, nullptr, zp, ml, bc, slot, y, 1);
        }
        fused_attn_kernel<<<dim3(SG, BATCH), 256, 0, stream>>>(
            hidden, y, zp, ml);
    }
    final_gemm<<<dim3(32, BATCH), 256, 0, stream>>>(
        WVT, zs, zp, ml, q, bV, out);
}

// Round 13
// 400.213 us; speedup vs baseline: 2.9547x; 1.4582x over previous
//
#include <hip/hip_runtime.h>

#define SEQ   512
#define BATCH 64
#define HID   1024
#define NX    8
#define SG    8      // s-groups per batch (attention); 64 rows each
#define SB    8      // rows per register batch
#define NBAT  8      // 8*8 = 64 rows per attn block

// ---------------------------------------------------------------------------
// WVT[h][n] = WV[n][h]  (one-time 32x32 tiled transpose)
// ---------------------------------------------------------------------------
__global__ __launch_bounds__(256) void transpose_k(
    const float* __restrict__ in, float* __restrict__ outT)
{
    __shared__ float tile[32][33];
    const int bx = blockIdx.x * 32, by = blockIdx.y * 32;
    const int tx = threadIdx.x & 31, ty = threadIdx.x >> 5;
    #pragma unroll
    for (int r = ty; r < 32; r += 8)
        tile[r][tx] = in[(size_t)(by + r) * HID + bx + tx];
    __syncthreads();
    #pragma unroll
    for (int r = ty; r < 32; r += 8)
        outT[(size_t)(bx + r) * HID + by + tx] = tile[tx][r];
}

// ---------------------------------------------------------------------------
// wc_gemm: WC[h,n] = sum_j WV[j,h] * WK[j,n]   (TN GEMM, one-time).
// grid (nt=32, mt=32) = 1024 blocks; 256 threads = 16x16, 2x2 acc each.
// A,B chunks staged [32][34] (aligned float2, conflict-free).
// ---------------------------------------------------------------------------
__global__ __launch_bounds__(256) void wc_gemm(
    const float* __restrict__ WV, const float* __restrict__ WK,
    float* __restrict__ WC)
{
    __shared__ float As[32][34];   // As[k][m_local]
    __shared__ float Bs[32][34];   // Bs[k][n_local]
    const int nt = blockIdx.x, mt = blockIdx.y;
    const int tid = threadIdx.x;
    const int nx = tid & 15, my = tid >> 4;

    float a00 = 0.f, a01 = 0.f, a10 = 0.f, a11 = 0.f;

    for (int k0 = 0; k0 < HID; k0 += 32) {
        {
            const int r = tid >> 3, c = (tid & 7) * 4;
            float4 av = *(const float4*)(WV + (size_t)(k0 + r) * HID + mt * 32 + c);
            As[r][c + 0] = av.x; As[r][c + 1] = av.y;
            As[r][c + 2] = av.z; As[r][c + 3] = av.w;
            float4 bv = *(const float4*)(WK + (size_t)(k0 + r) * HID + nt * 32 + c);
            Bs[r][c + 0] = bv.x; Bs[r][c + 1] = bv.y;
            Bs[r][c + 2] = bv.z; Bs[r][c + 3] = bv.w;
        }
        __syncthreads();
        #pragma unroll 8
        for (int kk = 0; kk < 32; kk++) {
            const float2 a = *(const float2*)&As[kk][my * 2];
            const float2 b = *(const float2*)&Bs[kk][nx * 2];
            a00 += a.x * b.x; a01 += a.x * b.y;
            a10 += a.y * b.x; a11 += a.y * b.y;
        }
        __syncthreads();
    }
    const int m = mt * 32 + my * 2, n = nt * 32 + nx * 2;
    WC[(size_t)m * HID + n]           = a00;
    WC[(size_t)m * HID + n + 1]       = a01;
    WC[(size_t)(m + 1) * HID + n]     = a10;
    WC[(size_t)(m + 1) * HID + n + 1] = a11;
}

// ---------------------------------------------------------------------------
// y_kernel: y[b,n] = sum_h x[b,h] * W[h,n] (+ bc[n])
// mode 0 (t==1): x = q, W = WK, no bc.     (also reused for bc = bV.WK)
// mode 1 (t>=2): x = rescale(zp, ml)  (global-softmax z), W = WC, + bc;
//                nc==0 also writes z to zs_slot (for the final out GEMM).
// grid (nc=32, b=64); block 256 = 8 jg x 32 nl.
// ---------------------------------------------------------------------------
__global__ __launch_bounds__(256) void y_kernel(
    const float* __restrict__ W, const float* __restrict__ q,
    const float* __restrict__ zp, const float* __restrict__ ml,
    const float* __restrict__ bc, float* __restrict__ zs_slot,
    float* __restrict__ y, int mode)
{
    __shared__ float xs[HID];
    __shared__ float red[8][32];
    const int nc = blockIdx.x, b = blockIdx.y;
    const int tid = threadIdx.x;

    if (mode == 0) {
        *(float4*)(xs + tid * 4) = *(const float4*)(q + (size_t)b * HID + tid * 4);
    } else {
        float M = -1e30f;
        #pragma unroll
        for (int g = 0; g < SG; g++) M = fmaxf(M, ml[b * 2 * SG + 2 * g]);
        float es[SG], L = 0.f;
        #pragma unroll
        for (int g = 0; g < SG; g++) {
            es[g] = __expf(ml[b * 2 * SG + 2 * g] - M);
            L += ml[b * 2 * SG + 2 * g + 1] * es[g];
        }
        const float invL = 1.0f / L;
        for (int i = tid; i < HID; i += 256) {
            float s = 0.f;
            #pragma unroll
            for (int g = 0; g < SG; g++)
                s += zp[((size_t)(b * SG + g)) * HID + i] * es[g];
            s *= invL;
            xs[i] = s;
            if (nc == 0 && zs_slot) zs_slot[(size_t)b * HID + i] = s;
        }
    }
    __syncthreads();

    const int nl = tid & 31, jg = tid >> 5;
    const int n = nc * 32 + nl;
    const float* __restrict__ wp = W + (size_t)(jg * 128) * HID + n;
    const float* __restrict__ xr = xs + jg * 128;
    float acc = 0.f;
    #pragma unroll 8
    for (int jj = 0; jj < 128; jj++)
        acc += xr[jj] * wp[(size_t)jj * HID];
    red[jg][nl] = acc;
    __syncthreads();
    if (tid < 32) {
        float s = 0.f;
        #pragma unroll
        for (int g = 0; g < 8; g++) s += red[g][tid];
        if (mode != 0) s += bc[nc * 32 + tid];
        y[(size_t)b * HID + nc * 32 + tid] = s;
    }
}

// ---------------------------------------------------------------------------
// fused_attn: grid (sg=8, b=64). 64 rows/block, online (m,l) flash; hidden
// rows in registers. Writes zp[b,sg,:] (unnormalized) and ml[b,sg]=(m,l).
// No fences, no atomics.
// ---------------------------------------------------------------------------
__global__ __launch_bounds__(256) void fused_attn_kernel(
    const float* __restrict__ hidden, const float* __restrict__ y,
    float* __restrict__ zp, float* __restrict__ ml)
{
    const int sg = blockIdx.x, b = blockIdx.y;
    const int tid = threadIdx.x;
    const int lane = tid & 63, w = tid >> 6;
    const int h4 = tid * 4;

    __shared__ float part[4][SB];

    const float4 yv = *(const float4*)(y + (size_t)b * HID + h4);
    float m = -1e30f, l = 0.f;
    float4 acc = {0.f, 0.f, 0.f, 0.f};

    for (int bb = 0; bb < NBAT; bb++) {
        float4 hv[SB];
        float p[SB];
        #pragma unroll
        for (int r = 0; r < SB; r++) {
            const int s = sg * 64 + bb * SB + r;
            hv[r] = *(const float4*)(hidden + ((size_t)s * BATCH + b) * HID + h4);
            p[r] = hv[r].x * yv.x + hv[r].y * yv.y
                 + hv[r].z * yv.z + hv[r].w * yv.w;
        }
        #pragma unroll
        for (int r = 0; r < SB; r++) {
            float s = p[r];
            #pragma unroll
            for (int off = 32; off; off >>= 1) s += __shfl_xor(s, off);
            if (lane == 0) part[w][r] = s;
        }
        __syncthreads();
        float sc[SB], mb = -1e30f;
        #pragma unroll
        for (int r = 0; r < SB; r++) {
            sc[r] = part[0][r] + part[1][r] + part[2][r] + part[3][r];
            mb = fmaxf(mb, sc[r]);
        }
        __syncthreads();
        const float newm  = fmaxf(m, mb);
        const float scale = __expf(m - newm);
        l *= scale;
        acc.x *= scale; acc.y *= scale; acc.z *= scale; acc.w *= scale;
        #pragma unroll
        for (int r = 0; r < SB; r++) {
            const float we = __expf(sc[r] - newm);
            l += we;
            acc.x += we * hv[r].x; acc.y += we * hv[r].y;
            acc.z += we * hv[r].z; acc.w += we * hv[r].w;
        }
        m = newm;
    }
    *(float4*)(zp + ((size_t)(b * SG + sg)) * HID + h4) = acc;
    if (tid == 0) {
        ml[(b * SG + sg) * 2 + 0] = m;
        ml[(b * SG + sg) * 2 + 1] = l;
    }
}

// ---------------------------------------------------------------------------
// final_gemm: out rows 1..7: out[b,s,n] = sum_h z_s[b,h]*WVT[h,n] + bV[n];
// z_s from zs slots (s=1..6) or from zp/ml (s=7). Row 0 = q.
// grid (nc=32, b=64); block 256 = 8 hg x 32 nl.
// ---------------------------------------------------------------------------
__global__ __launch_bounds__(256) void final_gemm(
    const float* __restrict__ WVT, const float* __restrict__ zs,
    const float* __restrict__ zp, const float* __restrict__ ml,
    const float* __restrict__ q, const float* __restrict__ bV,
    float* __restrict__ out)
{
    __shared__ float zst[7][HID];     // 28 KiB
    __shared__ float red[8][7][32];   // 7 KiB
    const int nc = blockIdx.x, b = blockIdx.y;
    const int tid = threadIdx.x;

    float M = -1e30f;
    #pragma unroll
    for (int g = 0; g < SG; g++) M = fmaxf(M, ml[b * 2 * SG + 2 * g]);
    float es[SG], L = 0.f;
    #pragma unroll
    for (int g = 0; g < SG; g++) {
        es[g] = __expf(ml[b * 2 * SG + 2 * g] - M);
        L += ml[b * 2 * SG + 2 * g + 1] * es[g];
    }
    const float invL = 1.0f / L;

    for (int i = tid; i < 7 * HID; i += 256) {
        const int si = i >> 10;          // 0..6  (step s = si+1)
        const int h  = i & (HID - 1);
        float v;
        if (si < 6) {
            v = zs[((size_t)si * BATCH + b) * HID + h];
        } else {
            v = 0.f;
            #pragma unroll
            for (int g = 0; g < SG; g++)
                v += zp[((size_t)(b * SG + g)) * HID + h] * es[g];
            v *= invL;
        }
        zst[si][h] = v;
    }
    __syncthreads();

    const int nl = tid & 31, hg = tid >> 5;
    const int n = nc * 32 + nl;
    const float* __restrict__ wp = WVT + (size_t)(hg * 128) * HID + n;
    float acc[7] = {};
    #pragma unroll 4
    for (int hh = 0; hh < 128; hh++) {
        const float wv = wp[(size_t)hh * HID];
        const int h = hg * 128 + hh;
        #pragma unroll
        for (int si = 0; si < 7; si++)
            acc[si] += zst[si][h] * wv;
    }
    #pragma unroll
    for (int si = 0; si < 7; si++) red[hg][si][nl] = acc[si];
    __syncthreads();

    if (tid < 224) {
        const int si = tid >> 5, nl2 = tid & 31;
        const int n2 = nc * 32 + nl2;
        float s = bV[n2];
        #pragma unroll
        for (int g = 0; g < 8; g++) s += red[g][si][nl2];
        out[((size_t)(b * NX + si + 1)) * HID + n2] = s;
    } else {
        const int nl2 = tid - 224;
        const int n2 = nc * 32 + nl2;
        out[((size_t)(b * NX)) * HID + n2] = q[(size_t)b * HID + n2];
    }
}

// ---------------------------------------------------------------------------
extern "C" void kernel_launch(void* const* d_in, const int* in_sizes, int n_in,
                              void* d_out, int out_size, void* d_ws, size_t ws_size,
                              hipStream_t stream)
{
    const float* hidden = (const float*)d_in[1];
    const float* q      = (const float*)d_in[2];
    const float* WK     = (const float*)d_in[3];
    const float* WV     = (const float*)d_in[5];
    const float* bV     = (const float*)d_in[6];
    float* out = (float*)d_out;

    char* ws = (char*)d_ws;
    float* WVT = (float*)(ws);                               // 4 MiB
    float* WC  = (float*)(ws + (4  << 20));                  // 4 MiB
    float* zp  = (float*)(ws + (8  << 20));                  // 2 MiB
    float* zs  = (float*)(ws + (10 << 20));                  // 6 slots, 1.5 MiB
    float* y   = (float*)(ws + (12 << 20));                  // 256 KiB
    float* ml  = (float*)(ws + (12 << 20) + (256 << 10));    // 4 KiB
    float* bc  = (float*)(ws + (12 << 20) + (512 << 10));    // 4 KiB

    transpose_k<<<dim3(32, 32), 256, 0, stream>>>(WV, WVT);
    wc_gemm<<<dim3(32, 32), 256, 0, stream>>>(WV, WK, WC);
    // bc = bV . WK  (reuse y_kernel mode 0 with x := bV, single "batch")
    y_kernel<<<dim3(32, 1), 256, 0, stream>>>(
        WK, bV, nullptr, nullptr, nullptr, nullptr, bc, 0);

    for (int t = 1; t < NX; t++) {
        if (t == 1) {
            y_kernel<<<dim3(32, BATCH), 256, 0, stream>>>(
                WK, q, nullptr, nullptr, nullptr, nullptr, y, 0);
        } else {
            float* slot = zs + (size_t)(t - 2) * BATCH * HID;
            y_kernel<<<dim3(32, BATCH), 256, 0, stream>>>(
                WC, nullptr, zp, ml, bc, slot, y, 1);
        }
        fused_attn_kernel<<<dim3(SG, BATCH), 256, 0, stream>>>(
            hidden, y, zp, ml);
    }
    final_gemm<<<dim3(32, BATCH), 256, 0, stream>>>(
        WVT, zs, zp, ml, q, bV, out);
}

// Round 14
// 372.355 us; speedup vs baseline: 3.1757x; 1.0748x over previous
//
#include <hip/hip_runtime.h>

#define SEQ   512
#define BATCH 64
#define HID   1024
#define NX    8
#define SG    8      // s-groups per batch (attention); 64 rows each
#define SB    8      // rows per register batch
#define NBAT  8      // 8*8 = 64 rows per attn block

// ---------------------------------------------------------------------------
// WVT[h][n] = WV[n][h]  (one-time 32x32 tiled transpose)
// ---------------------------------------------------------------------------
__global__ __launch_bounds__(256) void transpose_k(
    const float* __restrict__ in, float* __restrict__ outT)
{
    __shared__ float tile[32][33];
    const int bx = blockIdx.x * 32, by = blockIdx.y * 32;
    const int tx = threadIdx.x & 31, ty = threadIdx.x >> 5;
    #pragma unroll
    for (int r = ty; r < 32; r += 8)
        tile[r][tx] = in[(size_t)(by + r) * HID + bx + tx];
    __syncthreads();
    #pragma unroll
    for (int r = ty; r < 32; r += 8)
        outT[(size_t)(bx + r) * HID + by + tx] = tile[tx][r];
}

// ---------------------------------------------------------------------------
// wc_gemm: WC[h,n] = sum_j WV[j,h] * WK[j,n]   (TN GEMM, one-time).
// grid (nt=16, mt=16) = 256 blocks; 64x64 tile; 256 threads = 16x16, each
// with a 4x4 accumulator (16 FMA per 2 ds_read_b128 -> VALU-bound).
// BK=32; staging register-double-buffered to hide global latency.
// ---------------------------------------------------------------------------
__global__ __launch_bounds__(256) void wc_gemm(
    const float* __restrict__ WV, const float* __restrict__ WK,
    float* __restrict__ WC)
{
    __shared__ float As[32][68];   // As[k][m_local], pad 4
    __shared__ float Bs[32][68];   // Bs[k][n_local]
    const int nt = blockIdx.x, mt = blockIdx.y;
    const int tid = threadIdx.x;
    const int nx = tid & 15, my = tid >> 4;

    // staging map: thread -> (k-row r = tid>>3, col c = (tid&7)*8) 8 floats
    const int r = tid >> 3, c = (tid & 7) * 8;

    float acc[4][4] = {};

    // preload chunk 0
    float4 a0 = *(const float4*)(WV + (size_t)(0 + r) * HID + mt * 64 + c);
    float4 a1 = *(const float4*)(WV + (size_t)(0 + r) * HID + mt * 64 + c + 4);
    float4 b0 = *(const float4*)(WK + (size_t)(0 + r) * HID + nt * 64 + c);
    float4 b1 = *(const float4*)(WK + (size_t)(0 + r) * HID + nt * 64 + c + 4);

    for (int k0 = 0; k0 < HID; k0 += 32) {
        // write staged regs to LDS
        *(float4*)&As[r][c]     = a0;
        *(float4*)&As[r][c + 4] = a1;
        *(float4*)&Bs[r][c]     = b0;
        *(float4*)&Bs[r][c + 4] = b1;
        __syncthreads();

        // preload next chunk (latency hidden under compute below)
        if (k0 + 32 < HID) {
            a0 = *(const float4*)(WV + (size_t)(k0 + 32 + r) * HID + mt * 64 + c);
            a1 = *(const float4*)(WV + (size_t)(k0 + 32 + r) * HID + mt * 64 + c + 4);
            b0 = *(const float4*)(WK + (size_t)(k0 + 32 + r) * HID + nt * 64 + c);
            b1 = *(const float4*)(WK + (size_t)(k0 + 32 + r) * HID + nt * 64 + c + 4);
        }

        #pragma unroll 8
        for (int kk = 0; kk < 32; kk++) {
            const float4 a = *(const float4*)&As[kk][my * 4];
            const float4 b = *(const float4*)&Bs[kk][nx * 4];
            acc[0][0] += a.x * b.x; acc[0][1] += a.x * b.y;
            acc[0][2] += a.x * b.z; acc[0][3] += a.x * b.w;
            acc[1][0] += a.y * b.x; acc[1][1] += a.y * b.y;
            acc[1][2] += a.y * b.z; acc[1][3] += a.y * b.w;
            acc[2][0] += a.z * b.x; acc[2][1] += a.z * b.y;
            acc[2][2] += a.z * b.z; acc[2][3] += a.z * b.w;
            acc[3][0] += a.w * b.x; acc[3][1] += a.w * b.y;
            acc[3][2] += a.w * b.z; acc[3][3] += a.w * b.w;
        }
        __syncthreads();
    }

    const int m = mt * 64 + my * 4, n = nt * 64 + nx * 4;
    #pragma unroll
    for (int i = 0; i < 4; i++)
        *(float4*)(WC + (size_t)(m + i) * HID + n) = *(float4*)acc[i];
}

// ---------------------------------------------------------------------------
// y_kernel: y[b,n] = sum_h x[b,h] * W[h,n] (+ bc[n])
// mode 0 (t==1): x = q, W = WK, no bc.     (also reused for bc = bV.WK)
// mode 1 (t>=2): x = rescale(zp, ml)  (global-softmax z), W = WC, + bc;
//                nc==0 also writes z to zs_slot (for the final out GEMM).
// grid (nc=32, b=64); block 256 = 8 jg x 32 nl.
// ---------------------------------------------------------------------------
__global__ __launch_bounds__(256) void y_kernel(
    const float* __restrict__ W, const float* __restrict__ q,
    const float* __restrict__ zp, const float* __restrict__ ml,
    const float* __restrict__ bc, float* __restrict__ zs_slot,
    float* __restrict__ y, int mode)
{
    __shared__ float xs[HID];
    __shared__ float red[8][32];
    const int nc = blockIdx.x, b = blockIdx.y;
    const int tid = threadIdx.x;

    if (mode == 0) {
        *(float4*)(xs + tid * 4) = *(const float4*)(q + (size_t)b * HID + tid * 4);
    } else {
        float M = -1e30f;
        #pragma unroll
        for (int g = 0; g < SG; g++) M = fmaxf(M, ml[b * 2 * SG + 2 * g]);
        float es[SG], L = 0.f;
        #pragma unroll
        for (int g = 0; g < SG; g++) {
            es[g] = __expf(ml[b * 2 * SG + 2 * g] - M);
            L += ml[b * 2 * SG + 2 * g + 1] * es[g];
        }
        const float invL = 1.0f / L;
        for (int i = tid; i < HID; i += 256) {
            float s = 0.f;
            #pragma unroll
            for (int g = 0; g < SG; g++)
                s += zp[((size_t)(b * SG + g)) * HID + i] * es[g];
            s *= invL;
            xs[i] = s;
            if (nc == 0 && zs_slot) zs_slot[(size_t)b * HID + i] = s;
        }
    }
    __syncthreads();

    const int nl = tid & 31, jg = tid >> 5;
    const int n = nc * 32 + nl;
    const float* __restrict__ wp = W + (size_t)(jg * 128) * HID + n;
    const float* __restrict__ xr = xs + jg * 128;
    float acc = 0.f;
    #pragma unroll 8
    for (int jj = 0; jj < 128; jj++)
        acc += xr[jj] * wp[(size_t)jj * HID];
    red[jg][nl] = acc;
    __syncthreads();
    if (tid < 32) {
        float s = 0.f;
        #pragma unroll
        for (int g = 0; g < 8; g++) s += red[g][tid];
        if (mode != 0) s += bc[nc * 32 + tid];
        y[(size_t)b * HID + nc * 32 + tid] = s;
    }
}

// ---------------------------------------------------------------------------
// fused_attn: grid (sg=8, b=64). 64 rows/block, online (m,l) flash; hidden
// rows in registers. Writes zp[b,sg,:] (unnormalized) and ml[b,sg]=(m,l).
// No fences, no atomics.
// ---------------------------------------------------------------------------
__global__ __launch_bounds__(256) void fused_attn_kernel(
    const float* __restrict__ hidden, const float* __restrict__ y,
    float* __restrict__ zp, float* __restrict__ ml)
{
    const int sg = blockIdx.x, b = blockIdx.y;
    const int tid = threadIdx.x;
    const int lane = tid & 63, w = tid >> 6;
    const int h4 = tid * 4;

    __shared__ float part[4][SB];

    const float4 yv = *(const float4*)(y + (size_t)b * HID + h4);
    float m = -1e30f, l = 0.f;
    float4 acc = {0.f, 0.f, 0.f, 0.f};

    for (int bb = 0; bb < NBAT; bb++) {
        float4 hv[SB];
        float p[SB];
        #pragma unroll
        for (int r = 0; r < SB; r++) {
            const int s = sg * 64 + bb * SB + r;
            hv[r] = *(const float4*)(hidden + ((size_t)s * BATCH + b) * HID + h4);
            p[r] = hv[r].x * yv.x + hv[r].y * yv.y
                 + hv[r].z * yv.z + hv[r].w * yv.w;
        }
        #pragma unroll
        for (int r = 0; r < SB; r++) {
            float s = p[r];
            #pragma unroll
            for (int off = 32; off; off >>= 1) s += __shfl_xor(s, off);
            if (lane == 0) part[w][r] = s;
        }
        __syncthreads();
        float sc[SB], mb = -1e30f;
        #pragma unroll
        for (int r = 0; r < SB; r++) {
            sc[r] = part[0][r] + part[1][r] + part[2][r] + part[3][r];
            mb = fmaxf(mb, sc[r]);
        }
        __syncthreads();
        const float newm  = fmaxf(m, mb);
        const float scale = __expf(m - newm);
        l *= scale;
        acc.x *= scale; acc.y *= scale; acc.z *= scale; acc.w *= scale;
        #pragma unroll
        for (int r = 0; r < SB; r++) {
            const float we = __expf(sc[r] - newm);
            l += we;
            acc.x += we * hv[r].x; acc.y += we * hv[r].y;
            acc.z += we * hv[r].z; acc.w += we * hv[r].w;
        }
        m = newm;
    }
    *(float4*)(zp + ((size_t)(b * SG + sg)) * HID + h4) = acc;
    if (tid == 0) {
        ml[(b * SG + sg) * 2 + 0] = m;
        ml[(b * SG + sg) * 2 + 1] = l;
    }
}

// ---------------------------------------------------------------------------
// final_gemm: out rows 1..7: out[b,s,n] = sum_h z_s[b,h]*WVT[h,n] + bV[n];
// z_s from zs slots (s=1..6) or from zp/ml (s=7). Row 0 = q.
// grid (nc=32, b=64); block 256 = 8 hg x 32 nl.
// ---------------------------------------------------------------------------
__global__ __launch_bounds__(256) void final_gemm(
    const float* __restrict__ WVT, const float* __restrict__ zs,
    const float* __restrict__ zp, const float* __restrict__ ml,
    const float* __restrict__ q, const float* __restrict__ bV,
    float* __restrict__ out)
{
    __shared__ float zst[7][HID];     // 28 KiB
    __shared__ float red[8][7][32];   // 7 KiB
    const int nc = blockIdx.x, b = blockIdx.y;
    const int tid = threadIdx.x;

    float M = -1e30f;
    #pragma unroll
    for (int g = 0; g < SG; g++) M = fmaxf(M, ml[b * 2 * SG + 2 * g]);
    float es[SG], L = 0.f;
    #pragma unroll
    for (int g = 0; g < SG; g++) {
        es[g] = __expf(ml[b * 2 * SG + 2 * g] - M);
        L += ml[b * 2 * SG + 2 * g + 1] * es[g];
    }
    const float invL = 1.0f / L;

    for (int i = tid; i < 7 * HID; i += 256) {
        const int si = i >> 10;          // 0..6  (step s = si+1)
        const int h  = i & (HID - 1);
        float v;
        if (si < 6) {
            v = zs[((size_t)si * BATCH + b) * HID + h];
        } else {
            v = 0.f;
            #pragma unroll
            for (int g = 0; g < SG; g++)
                v += zp[((size_t)(b * SG + g)) * HID + h] * es[g];
            v *= invL;
        }
        zst[si][h] = v;
    }
    __syncthreads();

    const int nl = tid & 31, hg = tid >> 5;
    const int n = nc * 32 + nl;
    const float* __restrict__ wp = WVT + (size_t)(hg * 128) * HID + n;
    float acc[7] = {};
    #pragma unroll 4
    for (int hh = 0; hh < 128; hh++) {
        const float wv = wp[(size_t)hh * HID];
        const int h = hg * 128 + hh;
        #pragma unroll
        for (int si = 0; si < 7; si++)
            acc[si] += zst[si][h] * wv;
    }
    #pragma unroll
    for (int si = 0; si < 7; si++) red[hg][si][nl] = acc[si];
    __syncthreads();

    if (tid < 224) {
        const int si = tid >> 5, nl2 = tid & 31;
        const int n2 = nc * 32 + nl2;
        float s = bV[n2];
        #pragma unroll
        for (int g = 0; g < 8; g++) s += red[g][si][nl2];
        out[((size_t)(b * NX + si + 1)) * HID + n2] = s;
    } else {
        const int nl2 = tid - 224;
        const int n2 = nc * 32 + nl2;
        out[((size_t)(b * NX)) * HID + n2] = q[(size_t)b * HID + n2];
    }
}

// ---------------------------------------------------------------------------
extern "C" void kernel_launch(void* const* d_in, const int* in_sizes, int n_in,
                              void* d_out, int out_size, void* d_ws, size_t ws_size,
                              hipStream_t stream)
{
    const float* hidden = (const float*)d_in[1];
    const float* q      = (const float*)d_in[2];
    const float* WK     = (const float*)d_in[3];
    const float* WV     = (const float*)d_in[5];
    const float* bV     = (const float*)d_in[6];
    float* out = (float*)d_out;

    char* ws = (char*)d_ws;
    float* WVT = (float*)(ws);                               // 4 MiB
    float* WC  = (float*)(ws + (4  << 20));                  // 4 MiB
    float* zp  = (float*)(ws + (8  << 20));                  // 2 MiB
    float* zs  = (float*)(ws + (10 << 20));                  // 6 slots, 1.5 MiB
    float* y   = (float*)(ws + (12 << 20));                  // 256 KiB
    float* ml  = (float*)(ws + (12 << 20) + (256 << 10));    // 4 KiB
    float* bc  = (float*)(ws + (12 << 20) + (512 << 10));    // 4 KiB

    transpose_k<<<dim3(32, 32), 256, 0, stream>>>(WV, WVT);
    wc_gemm<<<dim3(16, 16), 256, 0, stream>>>(WV, WK, WC);
    // bc = bV . WK  (reuse y_kernel mode 0 with x := bV, single "batch")
    y_kernel<<<dim3(32, 1), 256, 0, stream>>>(
        WK, bV, nullptr, nullptr, nullptr, nullptr, bc, 0);

    for (int t = 1; t < NX; t++) {
        if (t == 1) {
            y_kernel<<<dim3(32, BATCH), 256, 0, stream>>>(
                WK, q, nullptr, nullptr, nullptr, nullptr, y, 0);
        } else {
            float* slot = zs + (size_t)(t - 2) * BATCH * HID;
            y_kernel<<<dim3(32, BATCH), 256, 0, stream>>>(
                WC, nullptr, zp, ml, bc, slot, y, 1);
        }
        fused_attn_kernel<<<dim3(SG, BATCH), 256, 0, stream>>>(
            hidden, y, zp, ml);
    }
    final_gemm<<<dim3(32, BATCH), 256, 0, stream>>>(
        WVT, zs, zp, ml, q, bV, out);
}